// Round 16
// baseline (910.014 us; speedup 1.0000x reference)
//
#include <hip/hip_runtime.h>

#define NUSER 50000
#define NITEM 50000
#define NTOT  100000
#define DFEAT 4096
#define DLAT  128
#define DHID  512
#define G1TILES 782          // ceil(50000/64)

typedef __attribute__((ext_vector_type(8))) short bf16x8;
typedef __attribute__((ext_vector_type(4))) float f32x4;

__device__ __forceinline__ ushort f2bf(float f) {
  union { float f; unsigned u; } in; in.f = f;
  unsigned u = in.u;
  u += 0x7fffu + ((u >> 16) & 1u);   // round-to-nearest-even
  return (ushort)(u >> 16);
}
// half-up rounding pack of two fp32 -> 2xbf16
__device__ __forceinline__ unsigned pk2bf_fast(float lo, float hi) {
  unsigned ul = __float_as_uint(lo) + 0x8000u;
  unsigned uh = __float_as_uint(hi) + 0x8000u;
  return (ul >> 16) | (uh & 0xffff0000u);
}
__device__ __forceinline__ float bflo(unsigned u) { return __uint_as_float(u << 16); }
__device__ __forceinline__ float bfhi(unsigned u) { return __uint_as_float(u & 0xffff0000u); }

// ========== fused MLP: X[item rows] = normalize(leakyrelu(A@W1+b1)@W2+b2) ==========
// R13 structure with BK=128 done as TWO independent 64-wide half-tiles:
// each half keeps the byte-identical R13 layout (128B row stride, XOR swizzle
// slot^=(row&7) — verified conflict-free), staged back-to-back before ONE
// barrier pair. Isolates "halve the barrier count" from R14's bank-conflict
// confound (R14 used one 256B-stride tile -> 2.7e7 conflicts, 3x regress).
// LDS 144KB (2x8KB A + 2x64KB B) -> 1 block/CU, same residency as 72KB.
__global__ __launch_bounds__(512, 4) void mlp_kernel(
    const float* __restrict__ A,     // [NITEM][DFEAT] fp32
    const ushort* __restrict__ W1T,  // [DHID][DFEAT] bf16
    const float* __restrict__ b1,    // [DHID]
    const ushort* __restrict__ W2T,  // [DLAT][DHID] bf16
    const float* __restrict__ b2,    // [DLAT]
    float* __restrict__ X,           // [NTOT][DLAT] (items at NUSER+)
    unsigned* __restrict__ Xb)       // [NTOT][64] bf16-pairs
{
  extern __shared__ char smem[];
  char* AsC0 = smem;                     // 8192 B  (A half 0; rsum scratch later)
  char* AsC1 = smem + 8192;              // 8192 B  (A half 1)
  char* BsC0 = smem + 16384;             // 65536 B (B half 0; hidden tile later)
  char* BsC1 = smem + 16384 + 65536;     // 65536 B (B half 1)
  float* rsumW = (float*)AsC0;

  const int tid = threadIdx.x;
  const int lane = tid & 63;
  const int wid = tid >> 6;          // 0..7
  const int row0 = blockIdx.x * 64;

  const int lr = lane & 15;
  const int kq = lane >> 4;          // 0..3
  const int l7 = lane & 7;

  f32x4 acc[4][4];
  const f32x4 z = {0.f, 0.f, 0.f, 0.f};
  #pragma unroll
  for (int m = 0; m < 4; ++m)
    #pragma unroll
    for (int n = 0; n < 4; ++n) acc[m][n] = z;

  // A staging (per half, exact R13 scheme): 512 16B-slots, 1/thread.
  // Rows clamped; pad-row garbage is per-row isolated, stores guarded below.
  const int r0 = tid >> 3, t0 = tid & 7;
  const int aoff = r0 * 128 + ((t0 ^ (r0 & 7)) << 4);
  const float* aptr = A + (size_t)min(row0 + r0, NITEM - 1) * DFEAT + t0 * 8;

  // ================= stage 1: hidden = leakyrelu(A@W1+b1) =================
  for (int k0 = 0; k0 < DFEAT; k0 += 128) {
    // ---- B stage: both halves, 8+8 gload_lds per wave, pre-swizzled src ----
    #pragma unroll
    for (int j = 0; j < 8; ++j) {
      int q = (wid * 8 + j) * 64 + lane;     // 0..4095
      int r = q >> 3, t = q & 7;
      size_t rowb = (size_t)r * DFEAT + ((t ^ (r & 7)) << 3);
      __builtin_amdgcn_global_load_lds(
          (const __attribute__((address_space(1))) void*)(W1T + rowb + k0),
          (__attribute__((address_space(3))) void*)(BsC0 + (size_t)(wid * 8 + j) * 1024),
          16, 0, 0);
      __builtin_amdgcn_global_load_lds(
          (const __attribute__((address_space(1))) void*)(W1T + rowb + k0 + 64),
          (__attribute__((address_space(3))) void*)(BsC1 + (size_t)(wid * 8 + j) * 1024),
          16, 0, 0);
    }
    // ---- A stage: both halves, fp32 -> bf16 -> swizzled ds_write ----
    {
      const float* s0 = aptr + k0;
      const float* s1 = aptr + k0 + 64;
      float4 v0 = *(const float4*)s0;
      float4 v1 = *(const float4*)(s0 + 4);
      float4 v2 = *(const float4*)s1;
      float4 v3 = *(const float4*)(s1 + 4);
      uint4 p0, p1;
      p0.x = pk2bf_fast(v0.x, v0.y); p0.y = pk2bf_fast(v0.z, v0.w);
      p0.z = pk2bf_fast(v1.x, v1.y); p0.w = pk2bf_fast(v1.z, v1.w);
      p1.x = pk2bf_fast(v2.x, v2.y); p1.y = pk2bf_fast(v2.z, v2.w);
      p1.z = pk2bf_fast(v3.x, v3.y); p1.w = pk2bf_fast(v3.z, v3.w);
      *(uint4*)(AsC0 + aoff) = p0;
      *(uint4*)(AsC1 + aoff) = p1;
    }
    __syncthreads();   // ONE drain for 144KB of staged data (vs two at BK=64)

    // ---- compute: 2 halves x 2 k-quarters x 16 MFMA (R13 inner loop x2) ----
    #pragma unroll
    for (int h = 0; h < 2; ++h) {
      const char* AsC = h ? AsC1 : AsC0;
      const char* BsC = h ? BsC1 : BsC0;
      #pragma unroll
      for (int kk = 0; kk < 2; ++kk) {
        const int c8 = kk * 4 + kq;
        const int sx = (c8 ^ l7) << 4;
        bf16x8 a[4], b[4];
        #pragma unroll
        for (int m = 0; m < 4; ++m)
          a[m] = *(const bf16x8*)(AsC + (m * 16 + lr) * 128 + sx);
        #pragma unroll
        for (int n = 0; n < 4; ++n)
          b[n] = *(const bf16x8*)(BsC + (wid * 64 + n * 16 + lr) * 128 + sx);
        #pragma unroll
        for (int m = 0; m < 4; ++m)
          #pragma unroll
          for (int n = 0; n < 4; ++n)
            acc[m][n] = __builtin_amdgcn_mfma_f32_16x16x32_bf16(a[m], b[n], acc[m][n], 0, 0, 0);
      }
    }
    __syncthreads();
  }

  // ============== stage 2a: hidden tile (bf16) -> BsC0, swizzled ==============
  // 64 rows x 512 cols, row stride 1024B; slot s of row r: (s&56)|((s&7)^(r&7)).
  #pragma unroll
  for (int n = 0; n < 4; ++n) {
    int col = wid * 64 + n * 16 + lr;
    float bv = b1[col];
    #pragma unroll
    for (int m = 0; m < 4; ++m)
      #pragma unroll
      for (int i = 0; i < 4; ++i) {
        float v = acc[m][n][i] + bv;
        v = v > 0.f ? v : 0.01f * v;
        float vo = __shfl_xor(v, 1, 64);
        if (!(lr & 1)) {
          int row = m * 16 + kq * 4 + i;
          int s = col >> 3;
          int sw = (s & 56) | ((s & 7) ^ (row & 7));
          *(unsigned*)(BsC0 + row * 1024 + sw * 16 + ((col * 2) & 15)) = pk2bf_fast(v, vo);
        }
      }
  }
  __syncthreads();

  // ============== stage 2b: out(64x128) = hidden @ W2, +b2 ==============
  f32x4 acc2[4];
  #pragma unroll
  for (int m = 0; m < 4; ++m) acc2[m] = z;
  const ushort* w2p = W2T + (size_t)(wid * 16 + lr) * DHID;
  #pragma unroll
  for (int ks = 0; ks < 16; ++ks) {
    bf16x8 b = *(const bf16x8*)(w2p + ks * 32 + kq * 8);
    #pragma unroll
    for (int m = 0; m < 4; ++m) {
      int row = m * 16 + lr;
      int s = ks * 4 + kq;
      int sw = (s & 56) | ((s & 7) ^ (row & 7));
      bf16x8 a = *(const bf16x8*)(BsC0 + row * 1024 + sw * 16);
      acc2[m] = __builtin_amdgcn_mfma_f32_16x16x32_bf16(a, b, acc2[m], 0, 0, 0);
    }
  }

  // ============== stage 2c: row L2-norm ==============
  const float bv2 = b2[wid * 16 + lr];
  float prt[4][4];
  #pragma unroll
  for (int m = 0; m < 4; ++m)
    #pragma unroll
    for (int i = 0; i < 4; ++i) {
      float v = acc2[m][i] + bv2;
      prt[m][i] = v * v;
    }
  #pragma unroll
  for (int msk = 1; msk < 16; msk <<= 1)
    #pragma unroll
    for (int m = 0; m < 4; ++m)
      #pragma unroll
      for (int i = 0; i < 4; ++i)
        prt[m][i] += __shfl_xor(prt[m][i], msk, 64);
  if (lr == 0) {
    #pragma unroll
    for (int m = 0; m < 4; ++m)
      #pragma unroll
      for (int i = 0; i < 4; ++i)
        rsumW[wid * 64 + m * 16 + kq * 4 + i] = prt[m][i];
  }
  __syncthreads();
  if (tid < 64) {
    float s = 0.f;
    #pragma unroll
    for (int w = 0; w < 8; ++w) s += rsumW[w * 64 + tid];
    rsumW[tid] = s;
  }
  __syncthreads();

  // ============== stage 2d: normalized store (X fp32 + Xb bf16) ==============
  #pragma unroll
  for (int m = 0; m < 4; ++m)
    #pragma unroll
    for (int i = 0; i < 4; ++i) {
      int rl = m * 16 + kq * 4 + i;
      int grow = row0 + rl;
      float inv = rsqrtf(fmaxf(rsumW[rl], 1e-24f));
      float v = (acc2[m][i] + bv2) * inv;
      float vo = __shfl_xor(v, 1, 64);
      if (grow < NITEM) {
        size_t node = (size_t)(NUSER + grow);
        int col = wid * 16 + lr;
        X[node * DLAT + col] = v;
        if (!(lr & 1))
          Xb[node * 64 + (col >> 1)] = pk2bf_fast(v, vo);
      }
    }
}

// ---------------- prep: coalesced LDS-tile transpose + fp32->bf16 ----------------
__global__ __launch_bounds__(256) void prep_w1t(const float* __restrict__ W1,
                                                ushort* __restrict__ W1T) {
  __shared__ ushort t[64][72];
  const int bx = blockIdx.x & 63;
  const int by = blockIdx.x >> 6;
  const int k0 = bx * 64, n0 = by * 64;
  const int tid = threadIdx.x;
  #pragma unroll
  for (int j = 0; j < 4; ++j) {
    int f = tid + j * 256;
    int r = f >> 4, c4 = (f & 15) << 2;
    float4 v = *(const float4*)(W1 + (size_t)(k0 + r) * DHID + n0 + c4);
    t[c4 + 0][r] = f2bf(v.x);
    t[c4 + 1][r] = f2bf(v.y);
    t[c4 + 2][r] = f2bf(v.z);
    t[c4 + 3][r] = f2bf(v.w);
  }
  __syncthreads();
  #pragma unroll
  for (int j = 0; j < 2; ++j) {
    int o = tid + j * 256;
    int r = o >> 3, c8 = (o & 7) << 3;
    *(uint4*)(W1T + (size_t)(n0 + r) * DFEAT + k0 + c8) = *(const uint4*)&t[r][c8];
  }
}
__global__ void prep_w2t(const float* __restrict__ W2, ushort* __restrict__ W2T) {
  int idx = blockIdx.x * 256 + threadIdx.x;
  int n = idx >> 9, k = idx & 511;
  W2T[idx] = f2bf(W2[(size_t)k * DLAT + n]);
}

// ------- normalize user rows -> X fp32 + Xb bf16; also raw passthrough -------
__global__ __launch_bounds__(256) void normalize_pref(
    const float* __restrict__ pref, float* __restrict__ X,
    unsigned* __restrict__ Xb, float* __restrict__ out2) {
  int gw = (blockIdx.x * 256 + threadIdx.x) >> 6;
  int lane = threadIdx.x & 63;
  if (gw >= NUSER) return;
  size_t o = (size_t)gw * DLAT + lane * 2;
  float2 v = *(const float2*)(pref + o);
  *(float2*)(out2 + o) = v;          // output 1: raw preference copy
  float s = v.x * v.x + v.y * v.y;
  #pragma unroll
  for (int off = 32; off; off >>= 1) s += __shfl_xor(s, off, 64);
  float inv = 1.0f / fmaxf(sqrtf(s), 1e-12f);
  float2 n; n.x = v.x * inv; n.y = v.y * inv;
  *(float2*)(X + o) = n;
  Xb[(size_t)gw * 64 + lane] = pk2bf_fast(n.x, n.y);
}

// ---------------- graph prep: CSR by destination ----------------
__global__ void count_kernel(const int* __restrict__ col, int* __restrict__ cnt, int E) {
  int e = blockIdx.x * 256 + threadIdx.x;
  if (e < E) atomicAdd(&cnt[col[e]], 1);
}

// ---------------- two-level scan ----------------
#define SCAN_NB ((NTOT + 1023) / 1024)   // 98
__global__ __launch_bounds__(1024) void scan1_kernel(const int* __restrict__ cnt,
                                                     int* __restrict__ off,
                                                     int* __restrict__ bsum, int n) {
  __shared__ int ws[16];
  __shared__ int wexcl[16];
  const int tid = threadIdx.x, lane = tid & 63, wv = tid >> 6;
  int i = blockIdx.x * 1024 + tid;
  int v = (i < n) ? cnt[i] : 0;
  int x = v;
  #pragma unroll
  for (int o = 1; o < 64; o <<= 1) {
    int t = __shfl_up(x, o, 64);
    if (lane >= o) x += t;
  }
  if (lane == 63) ws[wv] = x;
  __syncthreads();
  if (tid < 16) {
    int y = ws[tid];
    #pragma unroll
    for (int o = 1; o < 16; o <<= 1) {
      int t = __shfl_up(y, o, 64);
      if (tid >= o) y += t;
    }
    wexcl[tid] = y - ws[tid];
    if (tid == 15) bsum[blockIdx.x] = y;
  }
  __syncthreads();
  if (i < n) off[i] = wexcl[wv] + (x - v);
}
__global__ __launch_bounds__(128) void scan2_kernel(int* __restrict__ bsum,
                                                    int* __restrict__ off, int nb, int n) {
  __shared__ int ws[2];
  const int tid = threadIdx.x, lane = tid & 63, wv = tid >> 6;
  int v = (tid < nb) ? bsum[tid] : 0;
  int x = v;
  #pragma unroll
  for (int o = 1; o < 64; o <<= 1) {
    int t = __shfl_up(x, o, 64);
    if (lane >= o) x += t;
  }
  if (lane == 63) ws[wv] = x;
  __syncthreads();
  int excl_w = (wv == 1) ? ws[0] : 0;
  if (tid < nb) bsum[tid] = excl_w + (x - v);
  if (tid == nb - 1) off[n] = excl_w + x;
}
__global__ __launch_bounds__(1024) void scan3_kernel(int* __restrict__ off,
                                                     const int* __restrict__ bsum, int n) {
  int i = blockIdx.x * 1024 + threadIdx.x;
  if (i < n) off[i] += bsum[blockIdx.x];
}

// fill CSR slots: (src, edge-norm) per dst segment; dinv folded in
__global__ void fill_kernel(const int* __restrict__ row, const int* __restrict__ col,
                            const int* __restrict__ cnt, const int* __restrict__ off,
                            int* __restrict__ cur, int2* __restrict__ srcw, int E) {
  int e = blockIdx.x * 256 + threadIdx.x;
  if (e >= E) return;
  int r = row[e], c = col[e];
  float w = rsqrtf((float)cnt[r]) * rsqrtf((float)cnt[c]);
  int p = atomicAdd(&cur[c], 1);
  int2 pk; pk.x = r; pk.y = __float_as_int(w);
  srcw[off[c] + p] = pk;
}

// -------- SpMM: one wave per node, bf16 gathers, fp32 accumulate --------
template <int FINAL>
__global__ __launch_bounds__(256) void spmm_kernel(
    const int2* __restrict__ srcw, const int* __restrict__ off,
    const unsigned* __restrict__ hb, float* __restrict__ hout,
    unsigned* __restrict__ houtb,
    const float* __restrict__ addX, const unsigned* __restrict__ addH1) {
  int node = (int)((blockIdx.x * 256 + threadIdx.x) >> 6);
  int lane = threadIdx.x & 63;
  if (node >= NTOT) return;
  int p = off[node], pend = off[node + 1];
  float ax = 0.f, ay = 0.f;
  for (; p + 3 < pend; p += 4) {
    int2 e0 = srcw[p];
    int2 e1 = srcw[p + 1];
    int2 e2 = srcw[p + 2];
    int2 e3 = srcw[p + 3];
    unsigned u0 = hb[(size_t)e0.x * 64 + lane];
    unsigned u1 = hb[(size_t)e1.x * 64 + lane];
    unsigned u2 = hb[(size_t)e2.x * 64 + lane];
    unsigned u3 = hb[(size_t)e3.x * 64 + lane];
    float w0 = __int_as_float(e0.y), w1 = __int_as_float(e1.y);
    float w2 = __int_as_float(e2.y), w3 = __int_as_float(e3.y);
    ax += w0 * bflo(u0) + w1 * bflo(u1) + w2 * bflo(u2) + w3 * bflo(u3);
    ay += w0 * bfhi(u0) + w1 * bfhi(u1) + w2 * bfhi(u2) + w3 * bfhi(u3);
  }
  for (; p < pend; ++p) {
    int2 e0 = srcw[p];
    float w0 = __int_as_float(e0.y);
    unsigned u0 = hb[(size_t)e0.x * 64 + lane];
    ax += w0 * bflo(u0);
    ay += w0 * bfhi(u0);
  }
  if (FINAL) {
    size_t o = (size_t)node * DLAT + lane * 2;
    float2 a = *(const float2*)(addX + o);
    unsigned h1 = addH1[(size_t)node * 64 + lane];
    ax += a.x + bflo(h1);
    ay += a.y + bfhi(h1);
    float2 r; r.x = ax; r.y = ay;
    *(float2*)(hout + o) = r;
  } else {
    houtb[(size_t)node * 64 + lane] = pk2bf_fast(ax, ay);
  }
}

extern "C" void kernel_launch(void* const* d_in, const int* in_sizes, int n_in,
                              void* d_out, int out_size, void* d_ws, size_t ws_size,
                              hipStream_t stream) {
  const float* features  = (const float*)d_in[0];
  const float* preference = (const float*)d_in[1];
  const float* W1 = (const float*)d_in[2];
  const float* b1 = (const float*)d_in[3];
  const float* W2 = (const float*)d_in[4];
  const float* b2 = (const float*)d_in[5];
  const int*   edges = (const int*)d_in[6];
  const int E = in_sizes[6] / 2;
  const int* erow = edges;
  const int* ecol = edges + E;
  float* out = (float*)d_out;

  char* ws = (char*)d_ws;
  size_t off_b = 0;
  auto alloc = [&](size_t bytes) {
    void* p = ws + off_b;
    off_b = (off_b + bytes + 255) & ~(size_t)255;
    return p;
  };
  ushort*   W1T  = (ushort*)alloc((size_t)DHID * DFEAT * 2);   // 4.2 MB
  ushort*   W2T  = (ushort*)alloc((size_t)DLAT * DHID * 2);    // 0.13 MB
  float*    X    = (float*)alloc((size_t)NTOT * DLAT * 4);     // 51.2 MB
  unsigned* Xb   = (unsigned*)alloc((size_t)NTOT * 64 * 4);    // 25.6 MB
  unsigned* hAb  = (unsigned*)alloc((size_t)NTOT * 64 * 4);    // 25.6 MB
  int*      cnt  = (int*)alloc((size_t)NTOT * 4);
  int*      offs = (int*)alloc((size_t)(NTOT + 1) * 4);
  int*      cur  = (int*)alloc((size_t)NTOT * 4);
  int*      bsum = (int*)alloc((size_t)SCAN_NB * 4);
  int2*     srcw = (int2*)alloc((size_t)E * 8);                // 12.8 MB

  // fused projection MLP (+ item-row normalize); user rows + passthrough
  prep_w1t<<<512, 256, 0, stream>>>(W1, W1T);
  prep_w2t<<<(DLAT * DHID) / 256, 256, 0, stream>>>(W2, W2T);
  mlp_kernel<<<G1TILES, 512, 144 * 1024, stream>>>(features, W1T, b1, W2T, b2, X, Xb);
  normalize_pref<<<(NUSER * 64 + 255) / 256, 256, 0, stream>>>(
      preference, X, Xb, out + (size_t)NTOT * DLAT);

  // CSR build (by destination); symmetric edge list => cnt doubles as deg
  hipMemsetAsync(cnt, 0, (size_t)NTOT * 4, stream);
  count_kernel<<<(E + 255) / 256, 256, 0, stream>>>(ecol, cnt, E);
  scan1_kernel<<<SCAN_NB, 1024, 0, stream>>>(cnt, offs, bsum, NTOT);
  scan2_kernel<<<1, 128, 0, stream>>>(bsum, offs, SCAN_NB, NTOT);
  scan3_kernel<<<SCAN_NB, 1024, 0, stream>>>(offs, bsum, NTOT);
  hipMemsetAsync(cur, 0, (size_t)NTOT * 4, stream);
  fill_kernel<<<(E + 255) / 256, 256, 0, stream>>>(erow, ecol, cnt, offs, cur, srcw, E);

  // two propagation layers; layer 2 fuses out = X + h1 + h2
  spmm_kernel<0><<<(NTOT * 64 + 255) / 256, 256, 0, stream>>>(srcw, offs, Xb, nullptr, hAb, nullptr, nullptr);
  spmm_kernel<1><<<(NTOT * 64 + 255) / 256, 256, 0, stream>>>(srcw, offs, hAb, out, nullptr, X, hAb);
}

// Round 17
// 736.128 us; speedup vs baseline: 1.2362x; 1.2362x over previous
//
#include <hip/hip_runtime.h>

#define NUSER 50000
#define NITEM 50000
#define NTOT  100000
#define DFEAT 4096
#define DLAT  128
#define DHID  512
#define G1TILES 782          // ceil(50000/64)

typedef __attribute__((ext_vector_type(8))) short bf16x8;
typedef __attribute__((ext_vector_type(4))) float f32x4;

__device__ __forceinline__ ushort f2bf(float f) {
  union { float f; unsigned u; } in; in.f = f;
  unsigned u = in.u;
  u += 0x7fffu + ((u >> 16) & 1u);   // round-to-nearest-even
  return (ushort)(u >> 16);
}
// half-up rounding pack of two fp32 -> 2xbf16
__device__ __forceinline__ unsigned pk2bf_fast(float lo, float hi) {
  unsigned ul = __float_as_uint(lo) + 0x8000u;
  unsigned uh = __float_as_uint(hi) + 0x8000u;
  return (ul >> 16) | (uh & 0xffff0000u);
}
__device__ __forceinline__ float bflo(unsigned u) { return __uint_as_float(u << 16); }
__device__ __forceinline__ float bfhi(unsigned u) { return __uint_as_float(u & 0xffff0000u); }

// ========== fused MLP: X[item rows] = normalize(leakyrelu(A@W1+b1)@W2+b2) ==========
// FINAL KERNEL — R13 verbatim, best measured (739us total; mlp ~480us).
// BK=64, 72KB LDS, 2 barriers/step, XOR swizzle slot^=(row&7) (conflict-free).
// Plateau confirmed two-sided across 8 probes:
//  - pipelining (dbuf R6, T14-split R7, counted-vmcnt R9): all regressed —
//    __syncthreads drains vmcnt(0); cross-barrier in-flight unreachable here.
//  - barrier count (BK=128 single-tile R14: swizzle broke, 3x; BK=128
//    two-half same-swizzle R16: +30% — longer stage window LOWERS delivered BW).
//  - residency (launch_bounds R8: the one win; VGPR shave R11: null).
// Binding constraint: per-CU HBM delivery concurrency in the stage window.
__global__ __launch_bounds__(512, 4) void mlp_kernel(
    const float* __restrict__ A,     // [NITEM][DFEAT] fp32
    const ushort* __restrict__ W1T,  // [DHID][DFEAT] bf16
    const float* __restrict__ b1,    // [DHID]
    const ushort* __restrict__ W2T,  // [DLAT][DHID] bf16
    const float* __restrict__ b2,    // [DLAT]
    float* __restrict__ X,           // [NTOT][DLAT] (items at NUSER+)
    unsigned* __restrict__ Xb)       // [NTOT][64] bf16-pairs
{
  extern __shared__ char smem[];
  char* AsC = smem;             // 8192 B  (A tile; rsum scratch in epilogue)
  char* BsC = smem + 8192;      // 65536 B (B tile; hidden tile in epilogue)
  float* rsumW = (float*)AsC;

  const int tid = threadIdx.x;
  const int lane = tid & 63;
  const int wid = tid >> 6;          // 0..7
  const int row0 = blockIdx.x * 64;

  const int lr = lane & 15;
  const int kq = lane >> 4;          // 0..3
  const int l7 = lane & 7;

  f32x4 acc[4][4];
  const f32x4 z = {0.f, 0.f, 0.f, 0.f};
  #pragma unroll
  for (int m = 0; m < 4; ++m)
    #pragma unroll
    for (int n = 0; n < 4; ++n) acc[m][n] = z;

  const int r0 = tid >> 3, t0 = tid & 7;
  const int aoff = r0 * 128 + ((t0 ^ (r0 & 7)) << 4);
  const float* aptr = A + (size_t)min(row0 + r0, NITEM - 1) * DFEAT + t0 * 8;

  // ================= stage 1: hidden = leakyrelu(A@W1+b1) =================
  for (int k0 = 0; k0 < DFEAT; k0 += 64) {
    #pragma unroll
    for (int j = 0; j < 8; ++j) {
      int q = (wid * 8 + j) * 64 + lane;     // 0..4095
      int r = q >> 3, t = q & 7;
      const ushort* src = W1T + (size_t)r * DFEAT + k0 + ((t ^ (r & 7)) << 3);
      __builtin_amdgcn_global_load_lds(
          (const __attribute__((address_space(1))) void*)src,
          (__attribute__((address_space(3))) void*)(BsC + (size_t)(wid * 8 + j) * 1024),
          16, 0, 0);
    }
    {
      const float* s = aptr + k0;
      float4 v0 = *(const float4*)s;
      float4 v1 = *(const float4*)(s + 4);
      uint4 p;
      p.x = pk2bf_fast(v0.x, v0.y); p.y = pk2bf_fast(v0.z, v0.w);
      p.z = pk2bf_fast(v1.x, v1.y); p.w = pk2bf_fast(v1.z, v1.w);
      *(uint4*)(AsC + aoff) = p;
    }
    __syncthreads();

    #pragma unroll
    for (int kk = 0; kk < 2; ++kk) {
      const int c8 = kk * 4 + kq;
      const int sx = (c8 ^ l7) << 4;
      bf16x8 a[4], b[4];
      #pragma unroll
      for (int m = 0; m < 4; ++m)
        a[m] = *(const bf16x8*)(AsC + (m * 16 + lr) * 128 + sx);
      #pragma unroll
      for (int n = 0; n < 4; ++n)
        b[n] = *(const bf16x8*)(BsC + (wid * 64 + n * 16 + lr) * 128 + sx);
      #pragma unroll
      for (int m = 0; m < 4; ++m)
        #pragma unroll
        for (int n = 0; n < 4; ++n)
          acc[m][n] = __builtin_amdgcn_mfma_f32_16x16x32_bf16(a[m], b[n], acc[m][n], 0, 0, 0);
    }
    __syncthreads();
  }

  // ============== stage 2a: hidden tile (bf16) -> BsC, swizzled ==============
  #pragma unroll
  for (int n = 0; n < 4; ++n) {
    int col = wid * 64 + n * 16 + lr;
    float bv = b1[col];
    #pragma unroll
    for (int m = 0; m < 4; ++m)
      #pragma unroll
      for (int i = 0; i < 4; ++i) {
        float v = acc[m][n][i] + bv;
        v = v > 0.f ? v : 0.01f * v;
        float vo = __shfl_xor(v, 1, 64);
        if (!(lr & 1)) {
          int row = m * 16 + kq * 4 + i;
          int s = col >> 3;
          int sw = (s & 56) | ((s & 7) ^ (row & 7));
          *(unsigned*)(BsC + row * 1024 + sw * 16 + ((col * 2) & 15)) = pk2bf_fast(v, vo);
        }
      }
  }
  __syncthreads();

  // ============== stage 2b: out(64x128) = hidden @ W2, +b2 ==============
  f32x4 acc2[4];
  #pragma unroll
  for (int m = 0; m < 4; ++m) acc2[m] = z;
  const ushort* w2p = W2T + (size_t)(wid * 16 + lr) * DHID;
  #pragma unroll
  for (int ks = 0; ks < 16; ++ks) {
    bf16x8 b = *(const bf16x8*)(w2p + ks * 32 + kq * 8);
    #pragma unroll
    for (int m = 0; m < 4; ++m) {
      int row = m * 16 + lr;
      int s = ks * 4 + kq;
      int sw = (s & 56) | ((s & 7) ^ (row & 7));
      bf16x8 a = *(const bf16x8*)(BsC + row * 1024 + sw * 16);
      acc2[m] = __builtin_amdgcn_mfma_f32_16x16x32_bf16(a, b, acc2[m], 0, 0, 0);
    }
  }

  // ============== stage 2c: row L2-norm ==============
  const float bv2 = b2[wid * 16 + lr];
  float prt[4][4];
  #pragma unroll
  for (int m = 0; m < 4; ++m)
    #pragma unroll
    for (int i = 0; i < 4; ++i) {
      float v = acc2[m][i] + bv2;
      prt[m][i] = v * v;
    }
  #pragma unroll
  for (int msk = 1; msk < 16; msk <<= 1)
    #pragma unroll
    for (int m = 0; m < 4; ++m)
      #pragma unroll
      for (int i = 0; i < 4; ++i)
        prt[m][i] += __shfl_xor(prt[m][i], msk, 64);
  if (lr == 0) {
    #pragma unroll
    for (int m = 0; m < 4; ++m)
      #pragma unroll
      for (int i = 0; i < 4; ++i)
        rsumW[wid * 64 + m * 16 + kq * 4 + i] = prt[m][i];
  }
  __syncthreads();
  if (tid < 64) {
    float s = 0.f;
    #pragma unroll
    for (int w = 0; w < 8; ++w) s += rsumW[w * 64 + tid];
    rsumW[tid] = s;
  }
  __syncthreads();

  // ============== stage 2d: normalized store (X fp32 + Xb bf16) ==============
  #pragma unroll
  for (int m = 0; m < 4; ++m)
    #pragma unroll
    for (int i = 0; i < 4; ++i) {
      int rl = m * 16 + kq * 4 + i;
      int grow = row0 + rl;
      float inv = rsqrtf(fmaxf(rsumW[rl], 1e-24f));
      float v = (acc2[m][i] + bv2) * inv;
      float vo = __shfl_xor(v, 1, 64);
      if (grow < NITEM) {
        size_t node = (size_t)(NUSER + grow);
        int col = wid * 16 + lr;
        X[node * DLAT + col] = v;
        if (!(lr & 1))
          Xb[node * 64 + (col >> 1)] = pk2bf_fast(v, vo);
      }
    }
}

// ---------------- prep: coalesced LDS-tile transpose + fp32->bf16 ----------------
__global__ __launch_bounds__(256) void prep_w1t(const float* __restrict__ W1,
                                                ushort* __restrict__ W1T) {
  __shared__ ushort t[64][72];
  const int bx = blockIdx.x & 63;
  const int by = blockIdx.x >> 6;
  const int k0 = bx * 64, n0 = by * 64;
  const int tid = threadIdx.x;
  #pragma unroll
  for (int j = 0; j < 4; ++j) {
    int f = tid + j * 256;
    int r = f >> 4, c4 = (f & 15) << 2;
    float4 v = *(const float4*)(W1 + (size_t)(k0 + r) * DHID + n0 + c4);
    t[c4 + 0][r] = f2bf(v.x);
    t[c4 + 1][r] = f2bf(v.y);
    t[c4 + 2][r] = f2bf(v.z);
    t[c4 + 3][r] = f2bf(v.w);
  }
  __syncthreads();
  #pragma unroll
  for (int j = 0; j < 2; ++j) {
    int o = tid + j * 256;
    int r = o >> 3, c8 = (o & 7) << 3;
    *(uint4*)(W1T + (size_t)(n0 + r) * DFEAT + k0 + c8) = *(const uint4*)&t[r][c8];
  }
}
__global__ void prep_w2t(const float* __restrict__ W2, ushort* __restrict__ W2T) {
  int idx = blockIdx.x * 256 + threadIdx.x;
  int n = idx >> 9, k = idx & 511;
  W2T[idx] = f2bf(W2[(size_t)k * DLAT + n]);
}

// ------- normalize user rows -> X fp32 + Xb bf16; also raw passthrough -------
__global__ __launch_bounds__(256) void normalize_pref(
    const float* __restrict__ pref, float* __restrict__ X,
    unsigned* __restrict__ Xb, float* __restrict__ out2) {
  int gw = (blockIdx.x * 256 + threadIdx.x) >> 6;
  int lane = threadIdx.x & 63;
  if (gw >= NUSER) return;
  size_t o = (size_t)gw * DLAT + lane * 2;
  float2 v = *(const float2*)(pref + o);
  *(float2*)(out2 + o) = v;          // output 1: raw preference copy
  float s = v.x * v.x + v.y * v.y;
  #pragma unroll
  for (int off = 32; off; off >>= 1) s += __shfl_xor(s, off, 64);
  float inv = 1.0f / fmaxf(sqrtf(s), 1e-12f);
  float2 n; n.x = v.x * inv; n.y = v.y * inv;
  *(float2*)(X + o) = n;
  Xb[(size_t)gw * 64 + lane] = pk2bf_fast(n.x, n.y);
}

// ---------------- graph prep: CSR by destination ----------------
__global__ void count_kernel(const int* __restrict__ col, int* __restrict__ cnt, int E) {
  int e = blockIdx.x * 256 + threadIdx.x;
  if (e < E) atomicAdd(&cnt[col[e]], 1);
}

// ---------------- two-level scan ----------------
#define SCAN_NB ((NTOT + 1023) / 1024)   // 98
__global__ __launch_bounds__(1024) void scan1_kernel(const int* __restrict__ cnt,
                                                     int* __restrict__ off,
                                                     int* __restrict__ bsum, int n) {
  __shared__ int ws[16];
  __shared__ int wexcl[16];
  const int tid = threadIdx.x, lane = tid & 63, wv = tid >> 6;
  int i = blockIdx.x * 1024 + tid;
  int v = (i < n) ? cnt[i] : 0;
  int x = v;
  #pragma unroll
  for (int o = 1; o < 64; o <<= 1) {
    int t = __shfl_up(x, o, 64);
    if (lane >= o) x += t;
  }
  if (lane == 63) ws[wv] = x;
  __syncthreads();
  if (tid < 16) {
    int y = ws[tid];
    #pragma unroll
    for (int o = 1; o < 16; o <<= 1) {
      int t = __shfl_up(y, o, 64);
      if (tid >= o) y += t;
    }
    wexcl[tid] = y - ws[tid];
    if (tid == 15) bsum[blockIdx.x] = y;
  }
  __syncthreads();
  if (i < n) off[i] = wexcl[wv] + (x - v);
}
__global__ __launch_bounds__(128) void scan2_kernel(int* __restrict__ bsum,
                                                    int* __restrict__ off, int nb, int n) {
  __shared__ int ws[2];
  const int tid = threadIdx.x, lane = tid & 63, wv = tid >> 6;
  int v = (tid < nb) ? bsum[tid] : 0;
  int x = v;
  #pragma unroll
  for (int o = 1; o < 64; o <<= 1) {
    int t = __shfl_up(x, o, 64);
    if (lane >= o) x += t;
  }
  if (lane == 63) ws[wv] = x;
  __syncthreads();
  int excl_w = (wv == 1) ? ws[0] : 0;
  if (tid < nb) bsum[tid] = excl_w + (x - v);
  if (tid == nb - 1) off[n] = excl_w + x;
}
__global__ __launch_bounds__(1024) void scan3_kernel(int* __restrict__ off,
                                                     const int* __restrict__ bsum, int n) {
  int i = blockIdx.x * 1024 + threadIdx.x;
  if (i < n) off[i] += bsum[blockIdx.x];
}

// fill CSR slots: (src, edge-norm) per dst segment; dinv folded in
__global__ void fill_kernel(const int* __restrict__ row, const int* __restrict__ col,
                            const int* __restrict__ cnt, const int* __restrict__ off,
                            int* __restrict__ cur, int2* __restrict__ srcw, int E) {
  int e = blockIdx.x * 256 + threadIdx.x;
  if (e >= E) return;
  int r = row[e], c = col[e];
  float w = rsqrtf((float)cnt[r]) * rsqrtf((float)cnt[c]);
  int p = atomicAdd(&cur[c], 1);
  int2 pk; pk.x = r; pk.y = __float_as_int(w);
  srcw[off[c] + p] = pk;
}

// -------- SpMM: one wave per node, bf16 gathers, fp32 accumulate --------
template <int FINAL>
__global__ __launch_bounds__(256) void spmm_kernel(
    const int2* __restrict__ srcw, const int* __restrict__ off,
    const unsigned* __restrict__ hb, float* __restrict__ hout,
    unsigned* __restrict__ houtb,
    const float* __restrict__ addX, const unsigned* __restrict__ addH1) {
  int node = (int)((blockIdx.x * 256 + threadIdx.x) >> 6);
  int lane = threadIdx.x & 63;
  if (node >= NTOT) return;
  int p = off[node], pend = off[node + 1];
  float ax = 0.f, ay = 0.f;
  for (; p + 3 < pend; p += 4) {
    int2 e0 = srcw[p];
    int2 e1 = srcw[p + 1];
    int2 e2 = srcw[p + 2];
    int2 e3 = srcw[p + 3];
    unsigned u0 = hb[(size_t)e0.x * 64 + lane];
    unsigned u1 = hb[(size_t)e1.x * 64 + lane];
    unsigned u2 = hb[(size_t)e2.x * 64 + lane];
    unsigned u3 = hb[(size_t)e3.x * 64 + lane];
    float w0 = __int_as_float(e0.y), w1 = __int_as_float(e1.y);
    float w2 = __int_as_float(e2.y), w3 = __int_as_float(e3.y);
    ax += w0 * bflo(u0) + w1 * bflo(u1) + w2 * bflo(u2) + w3 * bflo(u3);
    ay += w0 * bfhi(u0) + w1 * bfhi(u1) + w2 * bfhi(u2) + w3 * bfhi(u3);
  }
  for (; p < pend; ++p) {
    int2 e0 = srcw[p];
    float w0 = __int_as_float(e0.y);
    unsigned u0 = hb[(size_t)e0.x * 64 + lane];
    ax += w0 * bflo(u0);
    ay += w0 * bfhi(u0);
  }
  if (FINAL) {
    size_t o = (size_t)node * DLAT + lane * 2;
    float2 a = *(const float2*)(addX + o);
    unsigned h1 = addH1[(size_t)node * 64 + lane];
    ax += a.x + bflo(h1);
    ay += a.y + bfhi(h1);
    float2 r; r.x = ax; r.y = ay;
    *(float2*)(hout + o) = r;
  } else {
    houtb[(size_t)node * 64 + lane] = pk2bf_fast(ax, ay);
  }
}

extern "C" void kernel_launch(void* const* d_in, const int* in_sizes, int n_in,
                              void* d_out, int out_size, void* d_ws, size_t ws_size,
                              hipStream_t stream) {
  const float* features  = (const float*)d_in[0];
  const float* preference = (const float*)d_in[1];
  const float* W1 = (const float*)d_in[2];
  const float* b1 = (const float*)d_in[3];
  const float* W2 = (const float*)d_in[4];
  const float* b2 = (const float*)d_in[5];
  const int*   edges = (const int*)d_in[6];
  const int E = in_sizes[6] / 2;
  const int* erow = edges;
  const int* ecol = edges + E;
  float* out = (float*)d_out;

  char* ws = (char*)d_ws;
  size_t off_b = 0;
  auto alloc = [&](size_t bytes) {
    void* p = ws + off_b;
    off_b = (off_b + bytes + 255) & ~(size_t)255;
    return p;
  };
  ushort*   W1T  = (ushort*)alloc((size_t)DHID * DFEAT * 2);   // 4.2 MB
  ushort*   W2T  = (ushort*)alloc((size_t)DLAT * DHID * 2);    // 0.13 MB
  float*    X    = (float*)alloc((size_t)NTOT * DLAT * 4);     // 51.2 MB
  unsigned* Xb   = (unsigned*)alloc((size_t)NTOT * 64 * 4);    // 25.6 MB
  unsigned* hAb  = (unsigned*)alloc((size_t)NTOT * 64 * 4);    // 25.6 MB
  int*      cnt  = (int*)alloc((size_t)NTOT * 4);
  int*      offs = (int*)alloc((size_t)(NTOT + 1) * 4);
  int*      cur  = (int*)alloc((size_t)NTOT * 4);
  int*      bsum = (int*)alloc((size_t)SCAN_NB * 4);
  int2*     srcw = (int2*)alloc((size_t)E * 8);                // 12.8 MB

  // fused projection MLP (+ item-row normalize); user rows + passthrough
  prep_w1t<<<512, 256, 0, stream>>>(W1, W1T);
  prep_w2t<<<(DLAT * DHID) / 256, 256, 0, stream>>>(W2, W2T);
  mlp_kernel<<<G1TILES, 512, 72 * 1024, stream>>>(features, W1T, b1, W2T, b2, X, Xb);
  normalize_pref<<<(NUSER * 64 + 255) / 256, 256, 0, stream>>>(
      preference, X, Xb, out + (size_t)NTOT * DLAT);

  // CSR build (by destination); symmetric edge list => cnt doubles as deg
  hipMemsetAsync(cnt, 0, (size_t)NTOT * 4, stream);
  count_kernel<<<(E + 255) / 256, 256, 0, stream>>>(ecol, cnt, E);
  scan1_kernel<<<SCAN_NB, 1024, 0, stream>>>(cnt, offs, bsum, NTOT);
  scan2_kernel<<<1, 128, 0, stream>>>(bsum, offs, SCAN_NB, NTOT);
  scan3_kernel<<<SCAN_NB, 1024, 0, stream>>>(offs, bsum, NTOT);
  hipMemsetAsync(cur, 0, (size_t)NTOT * 4, stream);
  fill_kernel<<<(E + 255) / 256, 256, 0, stream>>>(erow, ecol, cnt, offs, cur, srcw, E);

  // two propagation layers; layer 2 fuses out = X + h1 + h2
  spmm_kernel<0><<<(NTOT * 64 + 255) / 256, 256, 0, stream>>>(srcw, offs, Xb, nullptr, hAb, nullptr, nullptr);
  spmm_kernel<1><<<(NTOT * 64 + 255) / 256, 256, 0, stream>>>(srcw, offs, hAb, out, nullptr, X, hAb);
}